// Round 1
// baseline (2454.087 us; speedup 1.0000x reference)
//
#include <hip/hip_runtime.h>

#define N_NODES 16384
#define N_EDGES 32768
#define D 128
#define EDGE_DIM 10
#define EH 33   // 32 hidden + 1 bias row (h[e][32] = 1.0, B_32 = l2b)
#define BM 32   // edges per block in msg kernel

// h[e][k] = relu(ea[e]@l1w + l1b)[k], h[e][32] = 1.0
__global__ __launch_bounds__(256) void edge_mlp_kernel(
    const float* __restrict__ ea, const float* __restrict__ l1w,
    const float* __restrict__ l1b, float* __restrict__ h) {
  int e = blockIdx.x * blockDim.x + threadIdx.x;
  if (e >= N_EDGES) return;
  float a[EDGE_DIM];
#pragma unroll
  for (int d = 0; d < EDGE_DIM; d++) a[d] = ea[e * EDGE_DIM + d];
#pragma unroll
  for (int k = 0; k < 32; k++) {
    float acc = l1b[k];
#pragma unroll
    for (int d = 0; d < EDGE_DIM; d++) acc += a[d] * l1w[d * 32 + k];
    h[e * EH + k] = fmaxf(acc, 0.0f);
  }
  h[e * EH + 32] = 1.0f;
}

__global__ __launch_bounds__(256) void count_kernel(
    const int* __restrict__ ei, float* __restrict__ cnt) {
  int e = blockIdx.x * blockDim.x + threadIdx.x;
  if (e < N_EDGES) atomicAdd(&cnt[ei[N_EDGES + e]], 1.0f);
}

// Fused msg GEMM: msg[e][o] = sum_{k<33} h[e][k] * sum_i x[src_e][i]*B_k[i][o]
// with B_k = l2w row k reshaped [128][128] (k=32 -> l2b). Scatter-add to agg[dst].
__global__ __launch_bounds__(256) void msg_kernel(
    const float* __restrict__ xin, const float* __restrict__ h,
    const float* __restrict__ l2w, const float* __restrict__ l2b,
    const int* __restrict__ ei, float* __restrict__ agg) {
  __shared__ float Xs[BM][D];     // 16 KB gathered src features
  __shared__ float Hs[BM][EH];    // 4.2 KB edge-MLP outputs (+1.0 bias row)
  __shared__ float Bs[16][D];     // 8 KB staged B-slab
  __shared__ int Ds[BM];

  int t = threadIdx.x;
  int e0 = blockIdx.x * BM;

  if (t < BM) Ds[t] = ei[N_EDGES + e0 + t];
  {
    int r = t >> 3, l8 = t & 7;           // 8 threads per edge row
    int s = ei[e0 + r];
    const float4* xsrc = (const float4*)(xin + (size_t)s * D);
    float4* xd = (float4*)&Xs[r][0];
    for (int c = l8; c < D / 4; c += 8) xd[c] = xsrc[c];
  }
  for (int j = t; j < BM * EH; j += 256) ((float*)Hs)[j] = h[(size_t)e0 * EH + j];
  __syncthreads();

  int tx = t & 31, ty = t >> 5;
  int o0 = tx * 4, r0 = ty * 4;           // thread tile: 4 edges x 4 outputs
  float acc[4][4] = {};

  for (int k = 0; k < EH; k++) {
    const float* bsrc = (k < 32) ? (l2w + (size_t)k * (D * D)) : l2b;
    float hr[4];
#pragma unroll
    for (int jr = 0; jr < 4; jr++) hr[jr] = Hs[r0 + jr][k];
    for (int i0 = 0; i0 < D; i0 += 16) {
      __syncthreads();
      {
        const float4* bsv = (const float4*)(bsrc + i0 * D);
        for (int j = t; j < 16 * D / 4; j += 256) ((float4*)Bs)[j] = bsv[j];
      }
      __syncthreads();
#pragma unroll
      for (int ii = 0; ii < 16; ii++) {
        float4 b = *(const float4*)&Bs[ii][o0];
        float a0 = hr[0] * Xs[r0 + 0][i0 + ii];
        float a1 = hr[1] * Xs[r0 + 1][i0 + ii];
        float a2 = hr[2] * Xs[r0 + 2][i0 + ii];
        float a3 = hr[3] * Xs[r0 + 3][i0 + ii];
        acc[0][0] += a0 * b.x; acc[0][1] += a0 * b.y; acc[0][2] += a0 * b.z; acc[0][3] += a0 * b.w;
        acc[1][0] += a1 * b.x; acc[1][1] += a1 * b.y; acc[1][2] += a1 * b.z; acc[1][3] += a1 * b.w;
        acc[2][0] += a2 * b.x; acc[2][1] += a2 * b.y; acc[2][2] += a2 * b.z; acc[2][3] += a2 * b.w;
        acc[3][0] += a3 * b.x; acc[3][1] += a3 * b.y; acc[3][2] += a3 * b.z; acc[3][3] += a3 * b.w;
      }
    }
  }

#pragma unroll
  for (int jr = 0; jr < 4; jr++) {
    float* ag = agg + (size_t)Ds[r0 + jr] * D + o0;
#pragma unroll
    for (int jc = 0; jc < 4; jc++) atomicAdd(&ag[jc], acc[jr][jc]);
  }
}

// out[n][o] = (relu?) bias[o] + agg[n][o]/max(cnt[n],1) + sum_j x[n][j]*root[j][o]
__global__ __launch_bounds__(256) void node_update_kernel(
    const float* __restrict__ xin, const float* __restrict__ agg,
    const float* __restrict__ cnt, const float* __restrict__ root,
    const float* __restrict__ bias, float* __restrict__ out, int do_relu) {
  __shared__ float Xs[2][D];
  int t = threadIdx.x;
  int nn = t >> 7, o = t & 127;
  int n = blockIdx.x * 2 + nn;
  Xs[nn][o] = xin[(size_t)n * D + o];
  __syncthreads();
  float inv = 1.0f / fmaxf(cnt[n], 1.0f);
  float acc = bias[o] + inv * agg[(size_t)n * D + o];
#pragma unroll 4
  for (int j = 0; j < D; j++) acc += Xs[nn][j] * root[j * D + o];
  out[(size_t)n * D + o] = do_relu ? fmaxf(acc, 0.0f) : acc;
}

extern "C" void kernel_launch(void* const* d_in, const int* in_sizes, int n_in,
                              void* d_out, int out_size, void* d_ws, size_t ws_size,
                              hipStream_t stream) {
  const float* x      = (const float*)d_in[0];
  const int*   ei     = (const int*)d_in[1];
  const float* ea     = (const float*)d_in[2];
  const float* w1_l1  = (const float*)d_in[3];
  const float* b1_l1  = (const float*)d_in[4];
  const float* w1_l2  = (const float*)d_in[5];
  const float* b1_l2  = (const float*)d_in[6];
  const float* w1_rt  = (const float*)d_in[7];
  const float* b1     = (const float*)d_in[8];
  const float* w2_l1  = (const float*)d_in[9];
  const float* b2_l1  = (const float*)d_in[10];
  const float* w2_l2  = (const float*)d_in[11];
  const float* b2_l2  = (const float*)d_in[12];
  const float* w2_rt  = (const float*)d_in[13];
  const float* b2     = (const float*)d_in[14];
  float* out = (float*)d_out;

  float* h1   = (float*)d_ws;                   // E*33
  float* h2   = h1 + (size_t)N_EDGES * EH;      // E*33
  float* cnt  = h2 + (size_t)N_EDGES * EH;      // N
  float* agg  = cnt + N_NODES;                  // N*D
  float* nbuf = agg + (size_t)N_NODES * D;      // N*D

  hipMemsetAsync(cnt, 0, N_NODES * sizeof(float), stream);
  edge_mlp_kernel<<<N_EDGES / 256, 256, 0, stream>>>(ea, w1_l1, b1_l1, h1);
  edge_mlp_kernel<<<N_EDGES / 256, 256, 0, stream>>>(ea, w2_l1, b2_l1, h2);
  count_kernel<<<N_EDGES / 256, 256, 0, stream>>>(ei, cnt);

  // layer 1
  hipMemsetAsync(agg, 0, (size_t)N_NODES * D * sizeof(float), stream);
  msg_kernel<<<N_EDGES / BM, 256, 0, stream>>>(x, h1, w1_l2, b1_l2, ei, agg);
  node_update_kernel<<<N_NODES / 2, 256, 0, stream>>>(x, agg, cnt, w1_rt, b1, nbuf, 1);
  // layer 2
  hipMemsetAsync(agg, 0, (size_t)N_NODES * D * sizeof(float), stream);
  msg_kernel<<<N_EDGES / BM, 256, 0, stream>>>(nbuf, h2, w2_l2, b2_l2, ei, agg);
  node_update_kernel<<<N_NODES / 2, 256, 0, stream>>>(nbuf, agg, cnt, w2_rt, b2, nbuf, 1);
  // layer 3 (no relu)
  hipMemsetAsync(agg, 0, (size_t)N_NODES * D * sizeof(float), stream);
  msg_kernel<<<N_EDGES / BM, 256, 0, stream>>>(nbuf, h2, w2_l2, b2_l2, ei, agg);
  node_update_kernel<<<N_NODES / 2, 256, 0, stream>>>(nbuf, agg, cnt, w2_rt, b2, out, 0);
}

// Round 2
// 1050.603 us; speedup vs baseline: 2.3359x; 2.3359x over previous
//
#include <hip/hip_runtime.h>

#define N_NODES 16384
#define N_EDGES 32768
#define D 128
#define EDGE_DIM 10
#define KH 32          // edge-hidden dim (l2 bias folded out separately)
#define BM 64          // edges per msg block
#define XST 136        // Xs padded row stride in f16 (136*2B=272B: 2-way bank alias only)
#define NB 8           // nodes per node_update block

typedef _Float16 f16;
typedef _Float16 f16x4 __attribute__((ext_vector_type(4)));
typedef _Float16 f16x8 __attribute__((ext_vector_type(8)));
typedef float f32x4 __attribute__((ext_vector_type(4)));

// h[e][k] = relu(ea[e]@l1w + l1b)[k], stored f16 packed [E][32]
__global__ __launch_bounds__(256) void edge_mlp_kernel(
    const float* __restrict__ ea, const float* __restrict__ l1w,
    const float* __restrict__ l1b, f16* __restrict__ h) {
  int e = blockIdx.x * blockDim.x + threadIdx.x;
  if (e >= N_EDGES) return;
  float a[EDGE_DIM];
#pragma unroll
  for (int d = 0; d < EDGE_DIM; d++) a[d] = ea[e * EDGE_DIM + d];
#pragma unroll
  for (int k = 0; k < KH; k++) {
    float acc = l1b[k];
#pragma unroll
    for (int d = 0; d < EDGE_DIM; d++) acc += a[d] * l1w[d * KH + k];
    h[(size_t)e * KH + k] = (f16)fmaxf(acc, 0.0f);
  }
}

__global__ __launch_bounds__(256) void count_kernel(
    const int* __restrict__ ei, float* __restrict__ cnt) {
  int e = blockIdx.x * blockDim.x + threadIdx.x;
  if (e < N_EDGES) atomicAdd(&cnt[ei[N_EDGES + e]], 1.0f);
}

// l2w fp32 [32][128*128] (k,i*128+o) -> Bp f16 [i][o][k] (MFMA-B-fragment friendly)
__global__ __launch_bounds__(256) void pack_b_kernel(
    const float* __restrict__ l2w, f16* __restrict__ Bp) {
  int io = blockIdx.x * 256 + threadIdx.x;   // = i*128 + o
  f16 tmp[KH];
#pragma unroll
  for (int k = 0; k < KH; k++) tmp[k] = (f16)l2w[(size_t)k * (D * D) + io];
  f16x8* dst = (f16x8*)(Bp + (size_t)io * KH);
#pragma unroll
  for (int c = 0; c < 4; c++) dst[c] = *(f16x8*)&tmp[c * 8];
}

// msg GEMM via MFMA. K enumerated as i*32+k so each K-slab has constant i:
// A[m][kk] = h[e][kk] * x[e][i]  (h frag preloaded, x splat per slab).
// B operand read straight from L2-resident Bp[i][o][k]. Scatter-add into agg,
// plus xsum[dst] += x_src for the l2-bias matrix fold.
__global__ __launch_bounds__(256, 2) void msg_mfma_kernel(
    const float* __restrict__ xin, const f16* __restrict__ hf,
    const f16* __restrict__ Bp, const int* __restrict__ ei,
    float* __restrict__ agg, float* __restrict__ xsum) {
  __shared__ f16 Xs[BM][XST];
  __shared__ f16 Hs[BM][KH];
  __shared__ int Ds[BM];
  int t = threadIdx.x;
  int e0 = blockIdx.x * BM;

  if (t < BM) Ds[t] = ei[N_EDGES + e0 + t];
  // Hs flat copy: 64*32 = 2048 f16 = 256 * f16x8
  ((f16x8*)Hs)[t] = ((const f16x8*)(hf + (size_t)e0 * KH))[t];
  {
    int r = t >> 2, q = t & 3;
    int s = ei[e0 + r];
    const float4* src = (const float4*)(xin + (size_t)s * D + q * 32);
    f16* dst = &Xs[r][q * 32];
#pragma unroll
    for (int c = 0; c < 8; c++) {
      float4 v = src[c];
      f16x4 h4 = {(f16)v.x, (f16)v.y, (f16)v.z, (f16)v.w};
      *(f16x4*)(dst + c * 4) = h4;
    }
  }
  __syncthreads();

  int L = t & 63, w = t >> 6;
  int quad = L >> 4, lm = L & 15;
  int n0 = w * 32;

  f16x8 hreg[4];
#pragma unroll
  for (int mt = 0; mt < 4; mt++)
    hreg[mt] = *(const f16x8*)&Hs[mt * 16 + lm][quad * 8];

  // Bp fragment base for this lane: Bp[(i*128 + n0+nt*16+lm)*32 + quad*8]
  const f16* bl = Bp + (size_t)(n0 + lm) * KH + quad * 8;

  f32x4 acc[4][2];
#pragma unroll
  for (int mt = 0; mt < 4; mt++)
#pragma unroll
    for (int nt = 0; nt < 2; nt++)
      acc[mt][nt] = (f32x4){0.f, 0.f, 0.f, 0.f};

  for (int ig = 0; ig < D; ig += 8) {
    f16x8 xv[4];
#pragma unroll
    for (int mt = 0; mt < 4; mt++)
      xv[mt] = *(const f16x8*)&Xs[mt * 16 + lm][ig];
#pragma unroll
    for (int jj = 0; jj < 8; jj++) {
      const f16* bi = bl + (size_t)(ig + jj) * (D * KH);
      f16x8 b0 = *(const f16x8*)bi;
      f16x8 b1 = *(const f16x8*)(bi + 16 * KH);
#pragma unroll
      for (int mt = 0; mt < 4; mt++) {
        f16 xs = xv[mt][jj];
        f16x8 xb = {xs, xs, xs, xs, xs, xs, xs, xs};
        f16x8 a = hreg[mt] * xb;
        acc[mt][0] = __builtin_amdgcn_mfma_f32_16x16x32_f16(a, b0, acc[mt][0], 0, 0, 0);
        acc[mt][1] = __builtin_amdgcn_mfma_f32_16x16x32_f16(a, b1, acc[mt][1], 0, 0, 0);
      }
    }
  }

  // C/D layout: col = lane&15, row = quad*4 + reg (m89-verified)
#pragma unroll
  for (int mt = 0; mt < 4; mt++) {
    int eb = mt * 16 + quad * 4;
#pragma unroll
    for (int r = 0; r < 4; r++) {
      float* ag = agg + (size_t)Ds[eb + r] * D;
      atomicAdd(&ag[n0 + lm], acc[mt][0][r]);
      atomicAdd(&ag[n0 + 16 + lm], acc[mt][1][r]);
    }
  }
  // xsum scatter for bias fold (f16-rounded x: negligible extra error)
  {
    int er = t & 63, cb = (t >> 6) * 32;
    float* xd = xsum + (size_t)Ds[er] * D + cb;
#pragma unroll
    for (int c = 0; c < 32; c++)
      atomicAdd(&xd[c], (float)Xs[er][cb + c]);
  }
}

// out[n][o] = (relu?) bias[o] + (agg[n][o] + sum_j xsum[n][j]*bmat[j][o])/max(cnt,1)
//           + sum_j x[n][j]*root[j][o]
__global__ __launch_bounds__(256) void node_update_kernel(
    const float* __restrict__ xin, const float* __restrict__ agg,
    const float* __restrict__ xsum, const float* __restrict__ cnt,
    const float* __restrict__ root, const float* __restrict__ bmat,
    const float* __restrict__ bias, float* __restrict__ out, int do_relu) {
  __shared__ float Xls[NB][D];
  __shared__ float Sls[NB][D];
  int t = threadIdx.x;
  int o = t & 127, g = t >> 7;
  int nb = blockIdx.x * NB;
  for (int q = g; q < NB; q += 2) {
    Xls[q][o] = xin[(size_t)(nb + q) * D + o];
    Sls[q][o] = xsum[(size_t)(nb + q) * D + o];
  }
  __syncthreads();

  float ar[4] = {0.f, 0.f, 0.f, 0.f};
  float ab[4] = {0.f, 0.f, 0.f, 0.f};
  for (int jg = 0; jg < D; jg += 8) {
    float xr[4][8], sr[4][8];
#pragma unroll
    for (int k = 0; k < 4; k++) {
      int q = g + 2 * k;
      *(float4*)&xr[k][0] = *(const float4*)&Xls[q][jg];
      *(float4*)&xr[k][4] = *(const float4*)&Xls[q][jg + 4];
      *(float4*)&sr[k][0] = *(const float4*)&Sls[q][jg];
      *(float4*)&sr[k][4] = *(const float4*)&Sls[q][jg + 4];
    }
#pragma unroll
    for (int jj = 0; jj < 8; jj++) {
      float wr = root[(size_t)(jg + jj) * D + o];
      float wb = bmat[(size_t)(jg + jj) * D + o];
#pragma unroll
      for (int k = 0; k < 4; k++) {
        ar[k] += xr[k][jj] * wr;
        ab[k] += sr[k][jj] * wb;
      }
    }
  }
#pragma unroll
  for (int k = 0; k < 4; k++) {
    int n = nb + g + 2 * k;
    float inv = 1.0f / fmaxf(cnt[n], 1.0f);
    float v = bias[o] + inv * (agg[(size_t)n * D + o] + ab[k]) + ar[k];
    out[(size_t)n * D + o] = do_relu ? fmaxf(v, 0.0f) : v;
  }
}

extern "C" void kernel_launch(void* const* d_in, const int* in_sizes, int n_in,
                              void* d_out, int out_size, void* d_ws, size_t ws_size,
                              hipStream_t stream) {
  const float* x      = (const float*)d_in[0];
  const int*   ei     = (const int*)d_in[1];
  const float* ea     = (const float*)d_in[2];
  const float* w1_l1  = (const float*)d_in[3];
  const float* b1_l1  = (const float*)d_in[4];
  const float* w1_l2  = (const float*)d_in[5];
  const float* b1_l2  = (const float*)d_in[6];
  const float* w1_rt  = (const float*)d_in[7];
  const float* b1     = (const float*)d_in[8];
  const float* w2_l1  = (const float*)d_in[9];
  const float* b2_l1  = (const float*)d_in[10];
  const float* w2_l2  = (const float*)d_in[11];
  const float* b2_l2  = (const float*)d_in[12];
  const float* w2_rt  = (const float*)d_in[13];
  const float* b2     = (const float*)d_in[14];
  float* out = (float*)d_out;

  // workspace layout (~22.1 MB)
  f16* h1f = (f16*)d_ws;                                   // E*32 f16 (2 MB)
  f16* h2f = h1f + (size_t)N_EDGES * KH;                   // 2 MB
  f16* Bp1 = h2f + (size_t)N_EDGES * KH;                   // D*D*32 f16 (1 MB)
  f16* Bp2 = Bp1 + (size_t)D * D * KH;                     // 1 MB
  float* cnt  = (float*)(Bp2 + (size_t)D * D * KH);        // 64 KB
  float* agg  = cnt + N_NODES;                             // 8 MB
  float* xsum = agg + (size_t)N_NODES * D;                 // 8 MB

  hipMemsetAsync(cnt, 0, N_NODES * sizeof(float), stream);
  pack_b_kernel<<<D * D / 256, 256, 0, stream>>>(w1_l2, Bp1);
  pack_b_kernel<<<D * D / 256, 256, 0, stream>>>(w2_l2, Bp2);
  edge_mlp_kernel<<<N_EDGES / 256, 256, 0, stream>>>(ea, w1_l1, b1_l1, h1f);
  edge_mlp_kernel<<<N_EDGES / 256, 256, 0, stream>>>(ea, w2_l1, b2_l1, h2f);
  count_kernel<<<N_EDGES / 256, 256, 0, stream>>>(ei, cnt);

  // layer 1: x -> out (relu)
  hipMemsetAsync(agg, 0, (size_t)N_NODES * D * sizeof(float), stream);
  hipMemsetAsync(xsum, 0, (size_t)N_NODES * D * sizeof(float), stream);
  msg_mfma_kernel<<<N_EDGES / BM, 256, 0, stream>>>(x, h1f, Bp1, ei, agg, xsum);
  node_update_kernel<<<N_NODES / NB, 256, 0, stream>>>(x, agg, xsum, cnt, w1_rt, b1_l2, b1, out, 1);

  // layer 2: out -> out (relu)
  hipMemsetAsync(agg, 0, (size_t)N_NODES * D * sizeof(float), stream);
  hipMemsetAsync(xsum, 0, (size_t)N_NODES * D * sizeof(float), stream);
  msg_mfma_kernel<<<N_EDGES / BM, 256, 0, stream>>>(out, h2f, Bp2, ei, agg, xsum);
  node_update_kernel<<<N_NODES / NB, 256, 0, stream>>>(out, agg, xsum, cnt, w2_rt, b2_l2, b2, out, 1);

  // layer 3: out -> out (no relu)
  hipMemsetAsync(agg, 0, (size_t)N_NODES * D * sizeof(float), stream);
  hipMemsetAsync(xsum, 0, (size_t)N_NODES * D * sizeof(float), stream);
  msg_mfma_kernel<<<N_EDGES / BM, 256, 0, stream>>>(out, h2f, Bp2, ei, agg, xsum);
  node_update_kernel<<<N_NODES / NB, 256, 0, stream>>>(out, agg, xsum, cnt, w2_rt, b2_l2, b2, out, 0);
}

// Round 3
// 311.538 us; speedup vs baseline: 7.8773x; 3.3723x over previous
//
#include <hip/hip_runtime.h>

#define N_NODES 16384
#define N_EDGES 32768
#define D 128
#define EDGE_DIM 10
#define KH 32          // edge-hidden dim
#define BM 64          // edges per msg block
#define XST 136        // Xs padded row stride (f16)
#define NB 8           // nodes per node_update block

typedef _Float16 f16;
typedef _Float16 f16x4 __attribute__((ext_vector_type(4)));
typedef _Float16 f16x8 __attribute__((ext_vector_type(8)));
typedef float f32x4 __attribute__((ext_vector_type(4)));

// h[e][k] = relu(ea[e]@l1w + l1b)[k], f16 packed [E][32]
__global__ __launch_bounds__(256) void edge_mlp_kernel(
    const float* __restrict__ ea, const float* __restrict__ l1w,
    const float* __restrict__ l1b, f16* __restrict__ h) {
  int e = blockIdx.x * blockDim.x + threadIdx.x;
  if (e >= N_EDGES) return;
  float a[EDGE_DIM];
#pragma unroll
  for (int d = 0; d < EDGE_DIM; d++) a[d] = ea[e * EDGE_DIM + d];
#pragma unroll
  for (int k = 0; k < KH; k++) {
    float acc = l1b[k];
#pragma unroll
    for (int d = 0; d < EDGE_DIM; d++) acc += a[d] * l1w[d * KH + k];
    h[(size_t)e * KH + k] = (f16)fmaxf(acc, 0.0f);
  }
}

// ---- CSR build: deg count -> scan -> scatter(perm) ----
__global__ __launch_bounds__(256) void deg_count_kernel(
    const int* __restrict__ ei, int* __restrict__ deg) {
  int e = blockIdx.x * blockDim.x + threadIdx.x;
  if (e < N_EDGES) atomicAdd(&deg[ei[N_EDGES + e]], 1);
}

__global__ __launch_bounds__(1024) void scan_kernel(
    const int* __restrict__ deg, int* __restrict__ rs, int* __restrict__ fill) {
  __shared__ int part[1024];
  int t = threadIdx.x;
  int base = t * 16;
  int loc[16], s = 0;
#pragma unroll
  for (int j = 0; j < 16; j++) { loc[j] = deg[base + j]; s += loc[j]; }
  part[t] = s;
  __syncthreads();
  for (int off = 1; off < 1024; off <<= 1) {
    int add = (t >= off) ? part[t - off] : 0;
    __syncthreads();
    part[t] += add;
    __syncthreads();
  }
  int run = t ? part[t - 1] : 0;   // exclusive prefix
#pragma unroll
  for (int j = 0; j < 16; j++) {
    rs[base + j] = run; fill[base + j] = run; run += loc[j];
  }
  if (t == 1023) rs[N_NODES] = run;
}

__global__ __launch_bounds__(256) void scatter_kernel(
    const int* __restrict__ ei, int* __restrict__ fill, int* __restrict__ perm) {
  int e = blockIdx.x * blockDim.x + threadIdx.x;
  if (e < N_EDGES) {
    int pos = atomicAdd(&fill[ei[N_EDGES + e]], 1);
    perm[pos] = e;
  }
}

// l2w fp32 [32][128*128] (k, i*128+o) -> Bp f16 [i][o][k]
__global__ __launch_bounds__(256) void pack_b_kernel(
    const float* __restrict__ l2w, f16* __restrict__ Bp) {
  int io = blockIdx.x * 256 + threadIdx.x;   // = i*128 + o
  f16 tmp[KH];
#pragma unroll
  for (int k = 0; k < KH; k++) tmp[k] = (f16)l2w[(size_t)k * (D * D) + io];
  f16x8* dst = (f16x8*)(Bp + (size_t)io * KH);
#pragma unroll
  for (int c = 0; c < 4; c++) dst[c] = *(f16x8*)&tmp[c * 8];
}

// l2b fp32 [128*128] (i*128+o) -> Bb f16 [(i>>5)][o][i&31] (K=128 GEMM layout)
__global__ __launch_bounds__(256) void pack_bias_kernel(
    const float* __restrict__ l2b, f16* __restrict__ Bb) {
  int t = blockIdx.x * 256 + threadIdx.x;    // 0..16383
  int i = t >> 7, o = t & 127;
  Bb[((size_t)(i >> 5) * D + o) * KH + (i & 31)] = (f16)l2b[(size_t)i * D + o];
}

// msg GEMM via MFMA over dst-sorted edges; streams rows to msgbuf (no atomics).
// msg row for sorted-pos p = x[src]@(h@l2w + l2b) with the l2b matrix folded in
// as 4 extra K-slabs whose A-operand is x itself.
__global__ __launch_bounds__(256, 2) void msg_mfma_kernel(
    const float* __restrict__ xin, const f16* __restrict__ hf,
    const f16* __restrict__ Bp, const int* __restrict__ ei,
    const int* __restrict__ perm, float* __restrict__ msgbuf) {
  __shared__ f16 Xs[BM][XST];
  __shared__ f16 Hs[BM][KH];
  int t = threadIdx.x;
  int e0 = blockIdx.x * BM;

  {
    int r = t >> 2, q = t & 3;
    int es = perm[e0 + r];
    int s = ei[es];
    const float4* src = (const float4*)(xin + (size_t)s * D + q * 32);
    f16* dst = &Xs[r][q * 32];
#pragma unroll
    for (int c = 0; c < 8; c++) {
      float4 v = src[c];
      f16x4 h4 = {(f16)v.x, (f16)v.y, (f16)v.z, (f16)v.w};
      *(f16x4*)(dst + c * 4) = h4;
    }
    *(f16x8*)&Hs[r][q * 8] = *(const f16x8*)(hf + (size_t)es * KH + q * 8);
  }
  __syncthreads();

  int L = t & 63, w = t >> 6;
  int quad = L >> 4, lm = L & 15;
  int n0 = w * 32;

  f16x8 hreg[4];
#pragma unroll
  for (int mt = 0; mt < 4; mt++)
    hreg[mt] = *(const f16x8*)&Hs[mt * 16 + lm][quad * 8];

  const f16* bl = Bp + (size_t)(n0 + lm) * KH + quad * 8;

  f32x4 acc[4][2];
#pragma unroll
  for (int mt = 0; mt < 4; mt++)
#pragma unroll
    for (int nt = 0; nt < 2; nt++)
      acc[mt][nt] = (f32x4){0.f, 0.f, 0.f, 0.f};

  for (int ig = 0; ig < D; ig += 8) {
    f16x8 xv[4];
#pragma unroll
    for (int mt = 0; mt < 4; mt++)
      xv[mt] = *(const f16x8*)&Xs[mt * 16 + lm][ig];
#pragma unroll
    for (int jj = 0; jj < 8; jj++) {
      const f16* bi = bl + (size_t)(ig + jj) * (D * KH);
      f16x8 b0 = *(const f16x8*)bi;
      f16x8 b1 = *(const f16x8*)(bi + 16 * KH);
#pragma unroll
      for (int mt = 0; mt < 4; mt++) {
        f16 xs = xv[mt][jj];
        f16x8 xb = {xs, xs, xs, xs, xs, xs, xs, xs};
        f16x8 a = hreg[mt] * xb;
        acc[mt][0] = __builtin_amdgcn_mfma_f32_16x16x32_f16(a, b0, acc[mt][0], 0, 0, 0);
        acc[mt][1] = __builtin_amdgcn_mfma_f32_16x16x32_f16(a, b1, acc[mt][1], 0, 0, 0);
      }
    }
  }

  // l2b matrix fold: K=128 GEMM, A = x fragments straight from Xs
  {
    const f16* bb = Bp + (size_t)D * D * KH;
#pragma unroll
    for (int ig2 = 0; ig2 < 4; ig2++) {
      const f16* b2l = bb + ((size_t)ig2 * D + n0 + lm) * KH + quad * 8;
      f16x8 b0 = *(const f16x8*)b2l;
      f16x8 b1 = *(const f16x8*)(b2l + 16 * KH);
#pragma unroll
      for (int mt = 0; mt < 4; mt++) {
        f16x8 a = *(const f16x8*)&Xs[mt * 16 + lm][ig2 * 32 + quad * 8];
        acc[mt][0] = __builtin_amdgcn_mfma_f32_16x16x32_f16(a, b0, acc[mt][0], 0, 0, 0);
        acc[mt][1] = __builtin_amdgcn_mfma_f32_16x16x32_f16(a, b1, acc[mt][1], 0, 0, 0);
      }
    }
  }

  // C/D layout: col = lane&15, row = quad*4 + reg. Plain streaming stores.
#pragma unroll
  for (int mt = 0; mt < 4; mt++) {
#pragma unroll
    for (int r = 0; r < 4; r++) {
      float* mg = msgbuf + (size_t)(e0 + mt * 16 + quad * 4 + r) * D;
      mg[n0 + lm] = acc[mt][0][r];
      mg[n0 + 16 + lm] = acc[mt][1][r];
    }
  }
}

// out[n][o] = (relu?) bias[o] + (sum_{r in [rs[n],rs[n+1])} msgbuf[r][o])/max(deg,1)
//           + sum_j x[n][j]*root[j][o]
__global__ __launch_bounds__(256) void node_update_kernel(
    const float* __restrict__ xin, const float* __restrict__ msgbuf,
    const int* __restrict__ rs, const float* __restrict__ root,
    const float* __restrict__ bias, float* __restrict__ out, int do_relu) {
  __shared__ float Xls[NB][D];
  int t = threadIdx.x;
  int o = t & 127, g = t >> 7;
  int nb = blockIdx.x * NB;
  for (int q = g; q < NB; q += 2)
    Xls[q][o] = xin[(size_t)(nb + q) * D + o];
  __syncthreads();

  float aggm[4];
#pragma unroll
  for (int k = 0; k < 4; k++) {
    int n = nb + g + 2 * k;
    int a = rs[n], b = rs[n + 1];
    float s = 0.f;
    for (int r = a; r < b; r++) s += msgbuf[(size_t)r * D + o];
    aggm[k] = s / (float)max(b - a, 1);
  }

  float ar[4] = {0.f, 0.f, 0.f, 0.f};
  for (int jg = 0; jg < D; jg += 8) {
    float xr[4][8];
#pragma unroll
    for (int k = 0; k < 4; k++) {
      int q = g + 2 * k;
      *(float4*)&xr[k][0] = *(const float4*)&Xls[q][jg];
      *(float4*)&xr[k][4] = *(const float4*)&Xls[q][jg + 4];
    }
#pragma unroll
    for (int jj = 0; jj < 8; jj++) {
      float wr = root[(size_t)(jg + jj) * D + o];
#pragma unroll
      for (int k = 0; k < 4; k++) ar[k] += xr[k][jj] * wr;
    }
  }
#pragma unroll
  for (int k = 0; k < 4; k++) {
    int n = nb + g + 2 * k;
    float v = bias[o] + aggm[k] + ar[k];
    out[(size_t)n * D + o] = do_relu ? fmaxf(v, 0.0f) : v;
  }
}

extern "C" void kernel_launch(void* const* d_in, const int* in_sizes, int n_in,
                              void* d_out, int out_size, void* d_ws, size_t ws_size,
                              hipStream_t stream) {
  const float* x      = (const float*)d_in[0];
  const int*   ei     = (const int*)d_in[1];
  const float* ea     = (const float*)d_in[2];
  const float* w1_l1  = (const float*)d_in[3];
  const float* b1_l1  = (const float*)d_in[4];
  const float* w1_l2  = (const float*)d_in[5];
  const float* b1_l2  = (const float*)d_in[6];
  const float* w1_rt  = (const float*)d_in[7];
  const float* b1     = (const float*)d_in[8];
  const float* w2_l1  = (const float*)d_in[9];
  const float* b2_l1  = (const float*)d_in[10];
  const float* w2_l2  = (const float*)d_in[11];
  const float* b2_l2  = (const float*)d_in[12];
  const float* w2_rt  = (const float*)d_in[13];
  const float* b2     = (const float*)d_in[14];
  float* out = (float*)d_out;

  // workspace layout (~23.3 MB)
  const size_t BPSZ = (size_t)D * D * KH + (size_t)D * D;  // main + bias region (f16)
  f16* h1f = (f16*)d_ws;                                   // E*32 f16
  f16* h2f = h1f + (size_t)N_EDGES * KH;
  f16* Bp1 = h2f + (size_t)N_EDGES * KH;
  f16* Bp2 = Bp1 + BPSZ;
  int* deg  = (int*)(Bp2 + BPSZ);
  int* rs   = deg + N_NODES;                               // N+1 (+pad)
  int* fill = rs + N_NODES + 128;
  int* perm = fill + N_NODES;
  float* msgbuf = (float*)(perm + N_EDGES);                // E*D f32 (16.8 MB)

  hipMemsetAsync(deg, 0, N_NODES * sizeof(int), stream);
  pack_b_kernel<<<D * D / 256, 256, 0, stream>>>(w1_l2, Bp1);
  pack_bias_kernel<<<D * D / 256, 256, 0, stream>>>(b1_l2, Bp1 + (size_t)D * D * KH);
  pack_b_kernel<<<D * D / 256, 256, 0, stream>>>(w2_l2, Bp2);
  pack_bias_kernel<<<D * D / 256, 256, 0, stream>>>(b2_l2, Bp2 + (size_t)D * D * KH);
  edge_mlp_kernel<<<N_EDGES / 256, 256, 0, stream>>>(ea, w1_l1, b1_l1, h1f);
  edge_mlp_kernel<<<N_EDGES / 256, 256, 0, stream>>>(ea, w2_l1, b2_l1, h2f);
  deg_count_kernel<<<N_EDGES / 256, 256, 0, stream>>>(ei, deg);
  scan_kernel<<<1, 1024, 0, stream>>>(deg, rs, fill);
  scatter_kernel<<<N_EDGES / 256, 256, 0, stream>>>(ei, fill, perm);

  // layer 1: x -> out (relu)
  msg_mfma_kernel<<<N_EDGES / BM, 256, 0, stream>>>(x, h1f, Bp1, ei, perm, msgbuf);
  node_update_kernel<<<N_NODES / NB, 256, 0, stream>>>(x, msgbuf, rs, w1_rt, b1, out, 1);
  // layer 2: out -> out (relu)
  msg_mfma_kernel<<<N_EDGES / BM, 256, 0, stream>>>(out, h2f, Bp2, ei, perm, msgbuf);
  node_update_kernel<<<N_NODES / NB, 256, 0, stream>>>(out, msgbuf, rs, w2_rt, b2, out, 1);
  // layer 3: out -> out (no relu)
  msg_mfma_kernel<<<N_EDGES / BM, 256, 0, stream>>>(out, h2f, Bp2, ei, perm, msgbuf);
  node_update_kernel<<<N_NODES / NB, 256, 0, stream>>>(out, msgbuf, rs, w2_rt, b2, out, 0);
}